// Round 17
// baseline (404.238 us; speedup 1.0000x reference)
//
#include <hip/hip_runtime.h>
#include <math.h>

#define NB 32768
#define EPS_REC 1e-4f

// Inter-stage staging (static device globals: graph-capture safe).
__device__ float g_x2[NB * 256];  // stage-1 output: B x 16 x 16
__device__ float g_x3[NB * 16];   // stage-2 output: B x 4 x 4

// HISTORY (do not regress):
//  R5: dual-chain ILP -> occupancy halved, +22%. R6: reg-cap spills, +60%.
//  R8: 3 sweeps FAIL (absmax 1.375); 4 sweeps minimum (plateau 0.25-0.5).
//  R12-R19: register-carried column state across the pragma-unroll-1
//       back-edge -> ~430/850MB scratch regardless of form/shell/knobs.
//  R20: LDS-HOMED rounds -> scratch GONE (23.5/33MB ideal), VGPR 48,
//       stage1 447->236us, total 402us. LESSON 1: wave-lockstep iterative
//       state must be LDS-homed; intra-round register arrays are fine.
//  R21: source-level DPP caching: FLAT. LESSON 2: dpp_swap1 is pure ->
//       compiler already CSE'd. Count emitted ops, not source ops.
//  R22: packed f32 (pk_fma) + rsqrt-based rot: stage1 225us, total 393us.
//       Attribution: stage1 LDS pipe ~85% busy (162us structural b128 +
//       ~30us conflicts) vs VALU ~70% -> LDS binds.
//  R23/R24: exec-masked round loop: container failed twice (suspected
//       compile hang). LESSON 3: differentiate after two infra failures.
//  R25: stride 102 + dummy@611 (mod-8 bank theory): REGRESSION, conflicts
//       1.83e7 -> 4.10e7. LESSON 4: mod-8 model wrong; stride 100 +
//       dummy@600 is empirically best; A/B one variable at a time.
//  R26: revert to R22: reproduced (stage1 228us, conflicts 1.83e7, 392us).
//  R27 (this): single-variable A/B on the ONLY removable LDS term (~30us
//       conflicts): flip tournament movement from scatter-WRITE
//       (read own, write permf(sub)) to gather-READ (read srcslot(sub),
//       write own). Semantics identical (schedule phase-shift only; final
//       slot order irrelevant). Reads take the broadcast-capable conflict
//       path; writes become linear. If conflicts don't drop -> revert and
//       declare LDS-pipe roofline.
typedef float f32x2 __attribute__((ext_vector_type(2)));

__device__ __forceinline__ f32x2 mk2(float x, float y) {
  f32x2 r;
  r.x = x;
  r.y = y;
  return r;
}

__device__ __forceinline__ void wsync() {
  asm volatile("" ::: "memory");
  __builtin_amdgcn_wave_barrier();
  asm volatile("" ::: "memory");
}

// Swap values between adjacent lanes (lane ^ 1) via DPP quad_perm [1,0,3,2].
// Pairs (2k,2k+1) are even-aligned so they never cross a quad. VALU-pipe op.
__device__ __forceinline__ float dpp_swap1(float x) {
  int xi = __builtin_bit_cast(int, x);
  int yi = __builtin_amdgcn_update_dpp(xi, xi, 0xB1, 0xF, 0xF, true);
  return __builtin_bit_cast(float, yi);
}

// Tournament (circle-method): content of slot s moves to permf(s); with fixed
// pairing (2k,2k+1), every pair meets exactly once per N-1 rounds.
// srcslot = permf^{-1}: the slot whose content lands in slot `sub`.
__device__ __forceinline__ int srcslot(int sub, int n) {
  return sub == 0 ? 0
       : sub == 1 ? 2
       : sub == n - 2 ? n - 1
       : (sub & 1) ? sub - 2 : sub + 2;
}

// Jacobi rotation (c,s) zeroing the (p,q) off-diagonal of the 2x2 Gram
// [[app,apq],[apq,aqq]]; G = [[c,s],[-s,c]].  sqrt via x*rsqrt(x) (x>=1e-30).
__device__ __forceinline__ void rot_cs(float app, float aqq, float apq,
                                       float& c, float& s) {
  float dd = 0.5f * (app - aqq);
  float q2 = apq * apq;
  float hh = dd * dd + q2 + 1e-30f;
  float h = hh * rsqrtf(hh);  // == sqrt(hh), no IEEE fixup path
  float u = fabsf(dd) + h;
  float gi = rsqrtf(u * u + q2);
  c = u * gi;
  float smag = apq * gi;
  s = (dd >= 0.f) ? -smag : smag;
}

// One one-sided round, 20 rows, LDS-homed, gather-read movement:
// load column from srcslot (movement applied on read), DPP-swap, gram via
// pk-FMA, rot, apply via pk-FMA, store to OWN slot (linear write).
// All temporaries intra-round (dead at back-edge).
__device__ __forceinline__ void round20L(float4* SA4g, int sub, int rcol,
                                         bool isP) {
  f32x2 lo[5], hi[5], wl[5], wh[5];
#pragma unroll
  for (int t = 0; t < 5; ++t) {
    float4 a = SA4g[t * 20 + rcol];
    lo[t] = mk2(a.x, a.y);
    hi[t] = mk2(a.z, a.w);
    wl[t] = mk2(dpp_swap1(a.x), dpp_swap1(a.y));
    wh[t] = mk2(dpp_swap1(a.z), dpp_swap1(a.w));
  }
  f32x2 d2 = mk2(0.f, 0.f), n2 = mk2(0.f, 0.f);
#pragma unroll
  for (int t = 0; t < 5; ++t) {
    d2 = __builtin_elementwise_fma(lo[t], wl[t], d2);
    n2 = __builtin_elementwise_fma(lo[t], lo[t], n2);
    d2 = __builtin_elementwise_fma(hi[t], wh[t], d2);
    n2 = __builtin_elementwise_fma(hi[t], hi[t], n2);
  }
  float d = d2.x + d2.y;
  float nOwn = n2.x + n2.y;
  float nPrt = dpp_swap1(nOwn);
  float ne = isP ? nOwn : nPrt;  // canonical order: both pair lanes identical
  float no = isP ? nPrt : nOwn;
  float c, s;
  rot_cs(ne, no, d, c, s);
  float beta = isP ? -s : s;
  f32x2 cp = mk2(c, c), bp = mk2(beta, beta);
  wsync();  // all srcslot reads precede any overwrite (same-wave lockstep)
#pragma unroll
  for (int t = 0; t < 5; ++t) {
    f32x2 rlo = __builtin_elementwise_fma(wl[t], bp, lo[t] * cp);
    f32x2 rhi = __builtin_elementwise_fma(wh[t], bp, hi[t] * cp);
    SA4g[t * 20 + sub] = make_float4(rlo.x, rlo.y, rhi.x, rhi.y);
  }
  wsync();  // stores complete before next round's loads
}

// One one-sided round, 16 rows, LDS-homed, gather-read movement.
__device__ __forceinline__ void round16L(float4* SB4, int sub, int rcol,
                                         bool isP) {
  f32x2 lo[4], hi[4], wl[4], wh[4];
#pragma unroll
  for (int t = 0; t < 4; ++t) {
    float4 a = SB4[t * 16 + rcol];
    lo[t] = mk2(a.x, a.y);
    hi[t] = mk2(a.z, a.w);
    wl[t] = mk2(dpp_swap1(a.x), dpp_swap1(a.y));
    wh[t] = mk2(dpp_swap1(a.z), dpp_swap1(a.w));
  }
  f32x2 d2 = mk2(0.f, 0.f), n2 = mk2(0.f, 0.f);
#pragma unroll
  for (int t = 0; t < 4; ++t) {
    d2 = __builtin_elementwise_fma(lo[t], wl[t], d2);
    n2 = __builtin_elementwise_fma(lo[t], lo[t], n2);
    d2 = __builtin_elementwise_fma(hi[t], wh[t], d2);
    n2 = __builtin_elementwise_fma(hi[t], hi[t], n2);
  }
  float d = d2.x + d2.y;
  float nOwn = n2.x + n2.y;
  float nPrt = dpp_swap1(nOwn);
  float ne = isP ? nOwn : nPrt;
  float no = isP ? nPrt : nOwn;
  float c, s;
  rot_cs(ne, no, d, c, s);
  float beta = isP ? -s : s;
  f32x2 cp = mk2(c, c), bp = mk2(beta, beta);
  wsync();
#pragma unroll
  for (int t = 0; t < 4; ++t) {
    f32x2 rlo = __builtin_elementwise_fma(wl[t], bp, lo[t] * cp);
    f32x2 rhi = __builtin_elementwise_fma(wh[t], bp, hi[t] * cp);
    SB4[t * 16 + sub] = make_float4(rlo.x, rlo.y, rhi.x, rhi.y);
  }
  wsync();
}

// Stage 1: X1 = w1^T X w1 (19 padded to 20), one-sided Jacobi (LDS-homed),
// then X2 = Y^T Lamc Y with Y[j] = w2^T u_j. Final slot permutation is
// irrelevant: X2 sums over eigenpairs symmetrically. 3 matrices per wave
// (lanes 60..63 -> shared dummy slot 6), 128-thr blocks. R11 shell.
__global__ __launch_bounds__(128, 4) void spd_stage1(
    const float* __restrict__ x, const float* __restrict__ w1,
    const float* __restrict__ w2) {
  __shared__ float4 ZB[7 * 100];  // Z staging / column home / Y rows
  __shared__ float SL[7 * 20];
  int tid = threadIdx.x;
  int wid = tid >> 6;
  int lane = tid & 63;
  int gl = lane / 20;  // 0..3 (3 = idle lanes 60..63)
  int sub = lane - gl * 20;
  bool lane_ok = (gl < 3);
  int g = lane_ok ? (wid * 3 + gl) : 6;
  int b = blockIdx.x * 6 + g;
  bool valid = lane_ok && (b < NB);
  int bm = valid ? b : 0;
  float4* ZB4 = ZB + g * 100;
  float* ZBf = (float*)ZB4;
  float* SLg = SL + g * 20;

  // ---- bilinear: Z = w1^T X (col sub), then X1 col sub = (Z w1) col ----
  const float* xb = x + bm * 361;
  float cx[19];
#pragma unroll
  for (int i = 0; i < 19; ++i) cx[i] = (sub < 19) ? xb[i * 19 + sub] : 0.f;
  float z[20];
  z[19] = 0.f;
#pragma unroll
  for (int i = 0; i < 19; ++i) {
    float acc = 0.f;
#pragma unroll
    for (int r = 0; r < 19; ++r) acc += w1[r * 19 + i] * cx[r];
    z[i] = acc;
  }
#pragma unroll
  for (int t = 0; t < 5; ++t)
    ZB4[t * 20 + sub] =
        make_float4(z[4 * t], z[4 * t + 1], z[4 * t + 2], z[4 * t + 3]);
  wsync();
  float wj[19];
#pragma unroll
  for (int r = 0; r < 19; ++r) wj[r] = (sub < 19) ? w1[r * 19 + sub] : 0.f;
  float a1c[20];
#pragma unroll
  for (int i = 0; i < 20; ++i) a1c[i] = 0.f;
#pragma unroll
  for (int r = 0; r < 19; ++r) {
    float wr = wj[r];
#pragma unroll
    for (int t = 0; t < 5; ++t) {
      float4 zc = ZB4[t * 20 + r];  // Z rows 4t..4t+3, col r (broadcast)
      a1c[4 * t + 0] += zc.x * wr;
      a1c[4 * t + 1] += zc.y * wr;
      a1c[4 * t + 2] += zc.z * wr;
      a1c[4 * t + 3] += zc.w * wr;
    }
  }
  wsync();  // Z reads done; ZB becomes the column home
  // Store X1 column sub into home. Pad column 19 is exactly 0 (d=0 => s=0).
  // Dummy group 6 races -> garbage, confined to slot 6, never output.
#pragma unroll
  for (int t = 0; t < 5; ++t)
    ZB4[t * 20 + sub] = make_float4(a1c[4 * t], a1c[4 * t + 1],
                                    a1c[4 * t + 2], a1c[4 * t + 3]);
  wsync();

  const int rcol = srcslot(sub, 20);
  const bool isP = !(sub & 1);
#pragma unroll 1
  for (int it = 0; it < 76; ++it)  // 4 sweeps (validated minimum)
    round20L(ZB4, sub, rcol, isP);

  // Load final column; lambda_j = ||col||, u_j = col/||col||.
  float cv[20];
#pragma unroll
  for (int t = 0; t < 5; ++t) {
    float4 a = ZB4[t * 20 + sub];
    cv[4 * t + 0] = a.x;
    cv[4 * t + 1] = a.y;
    cv[4 * t + 2] = a.z;
    cv[4 * t + 3] = a.w;
  }
  float m0 = 0.f, m1 = 0.f;
#pragma unroll
  for (int i = 0; i < 20; i += 2) {
    m0 += cv[i] * cv[i];
    m1 += cv[i + 1] * cv[i + 1];
  }
  float nOwn = m0 + m1;
  float lamc = fmaxf(sqrtf(nOwn), EPS_REC);  // keep sqrtf: pad col is exact 0
  float nrm = nOwn + 1e-30f;
  float inv = rsqrtf(nrm);
  inv = inv * (1.5f - 0.5f * nrm * inv * inv);  // 1 NR step
  // y[k] = sum_{i<19} w2[i][k] * u_j[i]   (in-lane; w2 uniform -> scalar lds)
  float y[16];
#pragma unroll
  for (int k = 0; k < 16; ++k) y[k] = 0.f;
#pragma unroll
  for (int i = 0; i < 19; ++i) {
    float ui = cv[i];
#pragma unroll
    for (int k = 0; k < 16; ++k) y[k] += w2[i * 16 + k] * ui;
  }
#pragma unroll
  for (int k = 0; k < 16; ++k) y[k] *= inv;
  wsync();  // column home dead; reuse ZB for Y rows
  SLg[sub] = lamc;
#pragma unroll
  for (int t = 0; t < 4; ++t)
    ZB4[sub * 4 + t] =
        make_float4(y[4 * t], y[4 * t + 1], y[4 * t + 2], y[4 * t + 3]);
  wsync();
  // X2[i][sub] = sum_j lamc_j Y[j][i] Y[j][sub]  (order-independent sum)
  if (valid && sub < 16) {
    float acc[16];
#pragma unroll
    for (int i = 0; i < 16; ++i) acc[i] = 0.f;
#pragma unroll
    for (int r = 0; r < 20; ++r) {
      float pr = SLg[r] * ZBf[r * 16 + sub];
#pragma unroll
      for (int t = 0; t < 4; ++t) {
        float4 yr = ZB4[r * 4 + t];  // Y row r, cols 4t..4t+3 (broadcast)
        acc[4 * t + 0] += pr * yr.x;
        acc[4 * t + 1] += pr * yr.y;
        acc[4 * t + 2] += pr * yr.z;
        acc[4 * t + 3] += pr * yr.w;
      }
    }
    float* outb = g_x2 + b * 256;
#pragma unroll
    for (int i = 0; i < 16; ++i) outb[i * 16 + sub] = acc[i];
  }
}

// Stage 2: one-sided Jacobi on 16x16 (LDS-homed), X3 = Y3^T Lamc Y3 with
// Y3[j]=w3^T u_j. 4 matrices per wave, 128-thread blocks, all lanes active.
__global__ __launch_bounds__(128, 4) void spd_stage2(
    const float* __restrict__ w3) {
  __shared__ float4 SB[8 * 64];  // column home
  __shared__ float4 Y3L[8 * 16];
  __shared__ float SL2[8 * 16];
  int tid = threadIdx.x;
  int wid = tid >> 6;
  int lane = tid & 63;
  int gl = lane >> 4;
  int sub = lane & 15;
  int g = wid * 4 + gl;
  int b = blockIdx.x * 8 + g;
  float4* SB4 = SB + g * 64;
  float* Y3f = (float*)(Y3L + g * 16);
  float* SLg = SL2 + g * 16;

  const float* xb = g_x2 + b * 256;
  float ca[16];
#pragma unroll
  for (int i = 0; i < 16; ++i) ca[i] = xb[i * 16 + sub];
#pragma unroll
  for (int t = 0; t < 4; ++t)
    SB4[t * 16 + sub] =
        make_float4(ca[4 * t], ca[4 * t + 1], ca[4 * t + 2], ca[4 * t + 3]);
  wsync();

  const int rcol = srcslot(sub, 16);
  const bool isP = !(sub & 1);
#pragma unroll 1
  for (int it = 0; it < 60; ++it)  // 4 sweeps
    round16L(SB4, sub, rcol, isP);

  float cv[16];
#pragma unroll
  for (int t = 0; t < 4; ++t) {
    float4 a = SB4[t * 16 + sub];
    cv[4 * t + 0] = a.x;
    cv[4 * t + 1] = a.y;
    cv[4 * t + 2] = a.z;
    cv[4 * t + 3] = a.w;
  }
  float m0 = 0.f, m1 = 0.f;
#pragma unroll
  for (int i = 0; i < 16; i += 2) {
    m0 += cv[i] * cv[i];
    m1 += cv[i + 1] * cv[i + 1];
  }
  float nOwn = m0 + m1;
  float lamc = fmaxf(sqrtf(nOwn), EPS_REC);
  float nrm = nOwn + 1e-30f;
  float inv = rsqrtf(nrm);
  inv = inv * (1.5f - 0.5f * nrm * inv * inv);
  float y3[4] = {0.f, 0.f, 0.f, 0.f};
#pragma unroll
  for (int i = 0; i < 16; ++i) {
    float ui = cv[i];
#pragma unroll
    for (int j = 0; j < 4; ++j) y3[j] += w3[i * 4 + j] * ui;
  }
#pragma unroll
  for (int j = 0; j < 4; ++j) y3[j] *= inv;
  SLg[sub] = lamc;
  ((float4*)Y3f)[sub] = make_float4(y3[0], y3[1], y3[2], y3[3]);
  wsync();
  int ii = sub >> 2, jj = sub & 3;
  float acc = 0.f;
#pragma unroll
  for (int r = 0; r < 16; ++r)
    acc += SLg[r] * Y3f[r * 4 + ii] * Y3f[r * 4 + jj];
  g_x3[b * 16 + sub] = acc;
}

// Stage 3: per-thread 4x4 LogEig in registers, FC(16->2), log_softmax.
__global__ __launch_bounds__(256) void spd_stage3(const float* __restrict__ fcw,
                                                  float* __restrict__ out) {
  int b = blockIdx.x * 256 + threadIdx.x;
  const float* xb = g_x3 + b * 16;
  float a[4][4];
#pragma unroll
  for (int i = 0; i < 4; ++i)
#pragma unroll
    for (int j = 0; j < 4; ++j) a[i][j] = xb[i * 4 + j];
  float vv[4][4];
#pragma unroll
  for (int i = 0; i < 4; ++i)
#pragma unroll
    for (int j = 0; j < 4; ++j) vv[i][j] = (i == j) ? 1.f : 0.f;

  constexpr int P4[6] = {0, 0, 0, 1, 1, 2};
  constexpr int Q4[6] = {1, 2, 3, 2, 3, 3};
  for (int sw = 0; sw < 6; ++sw) {
#pragma unroll
    for (int e = 0; e < 6; ++e) {
      const int p = P4[e], q = Q4[e];
      float c, s;
      rot_cs(a[p][p], a[q][q], a[p][q], c, s);
#pragma unroll
      for (int j = 0; j < 4; ++j) {
        float xx = a[p][j], yy = a[q][j];
        a[p][j] = c * xx - s * yy;
        a[q][j] = s * xx + c * yy;
      }
#pragma unroll
      for (int i = 0; i < 4; ++i) {
        float xx = a[i][p], yy = a[i][q];
        a[i][p] = c * xx - s * yy;
        a[i][q] = s * xx + c * yy;
      }
#pragma unroll
      for (int i = 0; i < 4; ++i) {
        float xx = vv[i][p], yy = vv[i][q];
        vv[i][p] = c * xx - s * yy;
        vv[i][q] = s * xx + c * yy;
      }
    }
  }
  float ll[4];
#pragma unroll
  for (int r = 0; r < 4; ++r) ll[r] = logf(fmaxf(a[r][r], 1e-12f));
  float feat[16];
#pragma unroll
  for (int i = 0; i < 4; ++i)
#pragma unroll
    for (int j = 0; j < 4; ++j) {
      float acc = 0.f;
#pragma unroll
      for (int r = 0; r < 4; ++r) acc += ll[r] * vv[i][r] * vv[j][r];
      feat[i * 4 + j] = acc;
    }
  float z0 = 0.f, z1 = 0.f;
#pragma unroll
  for (int k = 0; k < 16; ++k) {
    z0 += feat[k] * fcw[2 * k + 0];
    z1 += feat[k] * fcw[2 * k + 1];
  }
  float m = fmaxf(z0, z1);
  float lse = logf(expf(z0 - m) + expf(z1 - m));
  out[b * 2 + 0] = z0 - m - lse;
  out[b * 2 + 1] = z1 - m - lse;
#pragma unroll
  for (int k = 0; k < 16; ++k) out[2 * NB + b * 16 + k] = feat[k];
}

extern "C" void kernel_launch(void* const* d_in, const int* in_sizes, int n_in,
                              void* d_out, int out_size, void* d_ws,
                              size_t ws_size, hipStream_t stream) {
  (void)in_sizes;
  (void)n_in;
  (void)out_size;
  (void)d_ws;
  (void)ws_size;
  const float* x = (const float*)d_in[0];
  const float* w1 = (const float*)d_in[1];
  const float* w2 = (const float*)d_in[2];
  const float* w3 = (const float*)d_in[3];
  const float* fcw = (const float*)d_in[4];
  float* out = (float*)d_out;

  spd_stage1<<<(NB + 5) / 6, 128, 0, stream>>>(x, w1, w2);
  spd_stage2<<<NB / 8, 128, 0, stream>>>(w3);
  spd_stage3<<<NB / 256, 256, 0, stream>>>(fcw, out);
}

// Round 18
// 378.742 us; speedup vs baseline: 1.0673x; 1.0673x over previous
//
#include <hip/hip_runtime.h>
#include <math.h>

#define NB 32768
#define EPS_REC 1e-4f

// Inter-stage staging (static device globals: graph-capture safe).
__device__ float g_x2[NB * 256];  // stage-1 output: B x 16 x 16
__device__ float g_x3[NB * 16];   // stage-2 output: B x 4 x 4

// HISTORY (do not regress):
//  R5: dual-chain ILP -> occupancy halved, +22%. R6: reg-cap spills, +60%.
//  R8: 3 sweeps FAIL (absmax 1.375); 4 sweeps minimum (plateau 0.25-0.5).
//  R12-R19: register-carried column state across the pragma-unroll-1
//       back-edge -> ~430/850MB scratch regardless of form/shell/knobs.
//  R20: LDS-HOMED rounds -> scratch GONE (23.5/33MB ideal), VGPR 48,
//       stage1 447->236us, total 402us. LESSON 1: wave-lockstep iterative
//       state must be LDS-homed; intra-round register arrays are fine.
//  R21: source-level DPP caching: FLAT. LESSON 2: compiler already CSE'd.
//  R22: packed f32 (pk_fma) + rsqrt rot: stage1 225us, total 393us.
//  R25: stride 102 + dummy@611: REGRESSION (conflicts 1.83e7->4.10e7).
//  R26: revert to R22: reproduced (228us / 1.83e7 / 392us).
//  R27: gather-read movement A/B: REGRESSION (conflicts 2.03e7, 404us).
//       R22/R26 layout is a verified local optimum on both sides.
//  R28 (this): final revert to the best measured config (R26 verbatim).
//  ROOFLINE: stage1 LDS pipe = 162us structural b128 + ~28us conflicts
//       = ~83% of 228us wall, VALU co-saturated ~70%, HBM at ideal,
//       sweeps at accuracy minimum. Register-residency (the only b128
//       reduction) is blocked by toolchain scratch (R12-R19). Remaining
//       headroom <= ~7% with both modeled attempts regressing.
typedef float f32x2 __attribute__((ext_vector_type(2)));

__device__ __forceinline__ f32x2 mk2(float x, float y) {
  f32x2 r;
  r.x = x;
  r.y = y;
  return r;
}

__device__ __forceinline__ void wsync() {
  asm volatile("" ::: "memory");
  __builtin_amdgcn_wave_barrier();
  asm volatile("" ::: "memory");
}

// Swap values between adjacent lanes (lane ^ 1) via DPP quad_perm [1,0,3,2].
// Pairs (2k,2k+1) are even-aligned so they never cross a quad. VALU-pipe op.
__device__ __forceinline__ float dpp_swap1(float x) {
  int xi = __builtin_bit_cast(int, x);
  int yi = __builtin_amdgcn_update_dpp(xi, xi, 0xB1, 0xF, 0xF, true);
  return __builtin_bit_cast(float, yi);
}

// Tournament (circle-method): content of slot s moves to permf(s); with fixed
// pairing (2k,2k+1), every pair meets exactly once per N-1 rounds.
__host__ __device__ constexpr int permf(int s, int n) {
  return s == 0 ? 0
       : s == 2 ? 1
       : (s & 1) ? (s == n - 1 ? n - 2 : s + 2)
       : s - 2;
}

// Jacobi rotation (c,s) zeroing the (p,q) off-diagonal of the 2x2 Gram
// [[app,apq],[apq,aqq]]; G = [[c,s],[-s,c]].  sqrt via x*rsqrt(x) (x>=1e-30).
__device__ __forceinline__ void rot_cs(float app, float aqq, float apq,
                                       float& c, float& s) {
  float dd = 0.5f * (app - aqq);
  float q2 = apq * apq;
  float hh = dd * dd + q2 + 1e-30f;
  float h = hh * rsqrtf(hh);  // == sqrt(hh), no IEEE fixup path
  float u = fabsf(dd) + h;
  float gi = rsqrtf(u * u + q2);
  c = u * gi;
  float smag = apq * gi;
  s = (dd >= 0.f) ? -smag : smag;
}

// One one-sided round, 20 rows, LDS-homed (R20 shape), packed-f32 math:
// load own column, DPP-swap once, gram via pk-FMA, rot, apply via pk-FMA,
// store to permuted slot. All temporaries intra-round (dead at back-edge).
__device__ __forceinline__ void round20L(float4* SA4g, int sub, int wcol,
                                         bool isP) {
  f32x2 lo[5], hi[5], wl[5], wh[5];
#pragma unroll
  for (int t = 0; t < 5; ++t) {
    float4 a = SA4g[t * 20 + sub];
    lo[t] = mk2(a.x, a.y);
    hi[t] = mk2(a.z, a.w);
    wl[t] = mk2(dpp_swap1(a.x), dpp_swap1(a.y));
    wh[t] = mk2(dpp_swap1(a.z), dpp_swap1(a.w));
  }
  f32x2 d2 = mk2(0.f, 0.f), n2 = mk2(0.f, 0.f);
#pragma unroll
  for (int t = 0; t < 5; ++t) {
    d2 = __builtin_elementwise_fma(lo[t], wl[t], d2);
    n2 = __builtin_elementwise_fma(lo[t], lo[t], n2);
    d2 = __builtin_elementwise_fma(hi[t], wh[t], d2);
    n2 = __builtin_elementwise_fma(hi[t], hi[t], n2);
  }
  float d = d2.x + d2.y;
  float nOwn = n2.x + n2.y;
  float nPrt = dpp_swap1(nOwn);
  float ne = isP ? nOwn : nPrt;  // canonical order: both pair lanes identical
  float no = isP ? nPrt : nOwn;
  float c, s;
  rot_cs(ne, no, d, c, s);
  float beta = isP ? -s : s;
  f32x2 cp = mk2(c, c), bp = mk2(beta, beta);
  wsync();  // all own-slot reads precede any overwrite (same-wave lockstep)
#pragma unroll
  for (int t = 0; t < 5; ++t) {
    f32x2 rlo = __builtin_elementwise_fma(wl[t], bp, lo[t] * cp);
    f32x2 rhi = __builtin_elementwise_fma(wh[t], bp, hi[t] * cp);
    SA4g[t * 20 + wcol] = make_float4(rlo.x, rlo.y, rhi.x, rhi.y);
  }
  wsync();  // stores complete before next round's loads
}

// One one-sided round, 16 rows, LDS-homed, packed-f32 math.
__device__ __forceinline__ void round16L(float4* SB4, int sub, int wcol,
                                         bool isP) {
  f32x2 lo[4], hi[4], wl[4], wh[4];
#pragma unroll
  for (int t = 0; t < 4; ++t) {
    float4 a = SB4[t * 16 + sub];
    lo[t] = mk2(a.x, a.y);
    hi[t] = mk2(a.z, a.w);
    wl[t] = mk2(dpp_swap1(a.x), dpp_swap1(a.y));
    wh[t] = mk2(dpp_swap1(a.z), dpp_swap1(a.w));
  }
  f32x2 d2 = mk2(0.f, 0.f), n2 = mk2(0.f, 0.f);
#pragma unroll
  for (int t = 0; t < 4; ++t) {
    d2 = __builtin_elementwise_fma(lo[t], wl[t], d2);
    n2 = __builtin_elementwise_fma(lo[t], lo[t], n2);
    d2 = __builtin_elementwise_fma(hi[t], wh[t], d2);
    n2 = __builtin_elementwise_fma(hi[t], hi[t], n2);
  }
  float d = d2.x + d2.y;
  float nOwn = n2.x + n2.y;
  float nPrt = dpp_swap1(nOwn);
  float ne = isP ? nOwn : nPrt;
  float no = isP ? nPrt : nOwn;
  float c, s;
  rot_cs(ne, no, d, c, s);
  float beta = isP ? -s : s;
  f32x2 cp = mk2(c, c), bp = mk2(beta, beta);
  wsync();
#pragma unroll
  for (int t = 0; t < 4; ++t) {
    f32x2 rlo = __builtin_elementwise_fma(wl[t], bp, lo[t] * cp);
    f32x2 rhi = __builtin_elementwise_fma(wh[t], bp, hi[t] * cp);
    SB4[t * 16 + wcol] = make_float4(rlo.x, rlo.y, rhi.x, rhi.y);
  }
  wsync();
}

// Stage 1: X1 = w1^T X w1 (19 padded to 20), one-sided Jacobi (LDS-homed),
// then X2 = Y^T Lamc Y with Y[j] = w2^T u_j. Final slot permutation is
// irrelevant: X2 sums over eigenpairs symmetrically. 3 matrices per wave
// (lanes 60..63 -> shared dummy slot 6), 128-thr blocks. R11 shell.
__global__ __launch_bounds__(128, 4) void spd_stage1(
    const float* __restrict__ x, const float* __restrict__ w1,
    const float* __restrict__ w2) {
  __shared__ float4 ZB[7 * 100];  // Z staging / column home / Y rows
  __shared__ float SL[7 * 20];
  int tid = threadIdx.x;
  int wid = tid >> 6;
  int lane = tid & 63;
  int gl = lane / 20;  // 0..3 (3 = idle lanes 60..63)
  int sub = lane - gl * 20;
  bool lane_ok = (gl < 3);
  int g = lane_ok ? (wid * 3 + gl) : 6;
  int b = blockIdx.x * 6 + g;
  bool valid = lane_ok && (b < NB);
  int bm = valid ? b : 0;
  float4* ZB4 = ZB + g * 100;
  float* ZBf = (float*)ZB4;
  float* SLg = SL + g * 20;

  // ---- bilinear: Z = w1^T X (col sub), then X1 col sub = (Z w1) col ----
  const float* xb = x + bm * 361;
  float cx[19];
#pragma unroll
  for (int i = 0; i < 19; ++i) cx[i] = (sub < 19) ? xb[i * 19 + sub] : 0.f;
  float z[20];
  z[19] = 0.f;
#pragma unroll
  for (int i = 0; i < 19; ++i) {
    float acc = 0.f;
#pragma unroll
    for (int r = 0; r < 19; ++r) acc += w1[r * 19 + i] * cx[r];
    z[i] = acc;
  }
#pragma unroll
  for (int t = 0; t < 5; ++t)
    ZB4[t * 20 + sub] =
        make_float4(z[4 * t], z[4 * t + 1], z[4 * t + 2], z[4 * t + 3]);
  wsync();
  float wj[19];
#pragma unroll
  for (int r = 0; r < 19; ++r) wj[r] = (sub < 19) ? w1[r * 19 + sub] : 0.f;
  float a1c[20];
#pragma unroll
  for (int i = 0; i < 20; ++i) a1c[i] = 0.f;
#pragma unroll
  for (int r = 0; r < 19; ++r) {
    float wr = wj[r];
#pragma unroll
    for (int t = 0; t < 5; ++t) {
      float4 zc = ZB4[t * 20 + r];  // Z rows 4t..4t+3, col r (broadcast)
      a1c[4 * t + 0] += zc.x * wr;
      a1c[4 * t + 1] += zc.y * wr;
      a1c[4 * t + 2] += zc.z * wr;
      a1c[4 * t + 3] += zc.w * wr;
    }
  }
  wsync();  // Z reads done; ZB becomes the column home
  // Store X1 column sub into home. Pad column 19 is exactly 0 (d=0 => s=0).
  // Dummy group 6 races -> garbage, confined to slot 6, never output.
#pragma unroll
  for (int t = 0; t < 5; ++t)
    ZB4[t * 20 + sub] = make_float4(a1c[4 * t], a1c[4 * t + 1],
                                    a1c[4 * t + 2], a1c[4 * t + 3]);
  wsync();

  const int wcol = permf(sub, 20);
  const bool isP = !(sub & 1);
#pragma unroll 1
  for (int it = 0; it < 76; ++it)  // 4 sweeps (validated minimum)
    round20L(ZB4, sub, wcol, isP);

  // Load final column; lambda_j = ||col||, u_j = col/||col||.
  float cv[20];
#pragma unroll
  for (int t = 0; t < 5; ++t) {
    float4 a = ZB4[t * 20 + sub];
    cv[4 * t + 0] = a.x;
    cv[4 * t + 1] = a.y;
    cv[4 * t + 2] = a.z;
    cv[4 * t + 3] = a.w;
  }
  float m0 = 0.f, m1 = 0.f;
#pragma unroll
  for (int i = 0; i < 20; i += 2) {
    m0 += cv[i] * cv[i];
    m1 += cv[i + 1] * cv[i + 1];
  }
  float nOwn = m0 + m1;
  float lamc = fmaxf(sqrtf(nOwn), EPS_REC);  // keep sqrtf: pad col is exact 0
  float nrm = nOwn + 1e-30f;
  float inv = rsqrtf(nrm);
  inv = inv * (1.5f - 0.5f * nrm * inv * inv);  // 1 NR step
  // y[k] = sum_{i<19} w2[i][k] * u_j[i]   (in-lane; w2 uniform -> scalar lds)
  float y[16];
#pragma unroll
  for (int k = 0; k < 16; ++k) y[k] = 0.f;
#pragma unroll
  for (int i = 0; i < 19; ++i) {
    float ui = cv[i];
#pragma unroll
    for (int k = 0; k < 16; ++k) y[k] += w2[i * 16 + k] * ui;
  }
#pragma unroll
  for (int k = 0; k < 16; ++k) y[k] *= inv;
  wsync();  // column home dead; reuse ZB for Y rows
  SLg[sub] = lamc;
#pragma unroll
  for (int t = 0; t < 4; ++t)
    ZB4[sub * 4 + t] =
        make_float4(y[4 * t], y[4 * t + 1], y[4 * t + 2], y[4 * t + 3]);
  wsync();
  // X2[i][sub] = sum_j lamc_j Y[j][i] Y[j][sub]  (order-independent sum)
  if (valid && sub < 16) {
    float acc[16];
#pragma unroll
    for (int i = 0; i < 16; ++i) acc[i] = 0.f;
#pragma unroll
    for (int r = 0; r < 20; ++r) {
      float pr = SLg[r] * ZBf[r * 16 + sub];
#pragma unroll
      for (int t = 0; t < 4; ++t) {
        float4 yr = ZB4[r * 4 + t];  // Y row r, cols 4t..4t+3 (broadcast)
        acc[4 * t + 0] += pr * yr.x;
        acc[4 * t + 1] += pr * yr.y;
        acc[4 * t + 2] += pr * yr.z;
        acc[4 * t + 3] += pr * yr.w;
      }
    }
    float* outb = g_x2 + b * 256;
#pragma unroll
    for (int i = 0; i < 16; ++i) outb[i * 16 + sub] = acc[i];
  }
}

// Stage 2: one-sided Jacobi on 16x16 (LDS-homed), X3 = Y3^T Lamc Y3 with
// Y3[j]=w3^T u_j. 4 matrices per wave, 128-thread blocks, all lanes active.
__global__ __launch_bounds__(128, 4) void spd_stage2(
    const float* __restrict__ w3) {
  __shared__ float4 SB[8 * 64];  // column home
  __shared__ float4 Y3L[8 * 16];
  __shared__ float SL2[8 * 16];
  int tid = threadIdx.x;
  int wid = tid >> 6;
  int lane = tid & 63;
  int gl = lane >> 4;
  int sub = lane & 15;
  int g = wid * 4 + gl;
  int b = blockIdx.x * 8 + g;
  float4* SB4 = SB + g * 64;
  float* Y3f = (float*)(Y3L + g * 16);
  float* SLg = SL2 + g * 16;

  const float* xb = g_x2 + b * 256;
  float ca[16];
#pragma unroll
  for (int i = 0; i < 16; ++i) ca[i] = xb[i * 16 + sub];
#pragma unroll
  for (int t = 0; t < 4; ++t)
    SB4[t * 16 + sub] =
        make_float4(ca[4 * t], ca[4 * t + 1], ca[4 * t + 2], ca[4 * t + 3]);
  wsync();

  const int wcol = permf(sub, 16);
  const bool isP = !(sub & 1);
#pragma unroll 1
  for (int it = 0; it < 60; ++it)  // 4 sweeps
    round16L(SB4, sub, wcol, isP);

  float cv[16];
#pragma unroll
  for (int t = 0; t < 4; ++t) {
    float4 a = SB4[t * 16 + sub];
    cv[4 * t + 0] = a.x;
    cv[4 * t + 1] = a.y;
    cv[4 * t + 2] = a.z;
    cv[4 * t + 3] = a.w;
  }
  float m0 = 0.f, m1 = 0.f;
#pragma unroll
  for (int i = 0; i < 16; i += 2) {
    m0 += cv[i] * cv[i];
    m1 += cv[i + 1] * cv[i + 1];
  }
  float nOwn = m0 + m1;
  float lamc = fmaxf(sqrtf(nOwn), EPS_REC);
  float nrm = nOwn + 1e-30f;
  float inv = rsqrtf(nrm);
  inv = inv * (1.5f - 0.5f * nrm * inv * inv);
  float y3[4] = {0.f, 0.f, 0.f, 0.f};
#pragma unroll
  for (int i = 0; i < 16; ++i) {
    float ui = cv[i];
#pragma unroll
    for (int j = 0; j < 4; ++j) y3[j] += w3[i * 4 + j] * ui;
  }
#pragma unroll
  for (int j = 0; j < 4; ++j) y3[j] *= inv;
  SLg[sub] = lamc;
  ((float4*)Y3f)[sub] = make_float4(y3[0], y3[1], y3[2], y3[3]);
  wsync();
  int ii = sub >> 2, jj = sub & 3;
  float acc = 0.f;
#pragma unroll
  for (int r = 0; r < 16; ++r)
    acc += SLg[r] * Y3f[r * 4 + ii] * Y3f[r * 4 + jj];
  g_x3[b * 16 + sub] = acc;
}

// Stage 3: per-thread 4x4 LogEig in registers, FC(16->2), log_softmax.
__global__ __launch_bounds__(256) void spd_stage3(const float* __restrict__ fcw,
                                                  float* __restrict__ out) {
  int b = blockIdx.x * 256 + threadIdx.x;
  const float* xb = g_x3 + b * 16;
  float a[4][4];
#pragma unroll
  for (int i = 0; i < 4; ++i)
#pragma unroll
    for (int j = 0; j < 4; ++j) a[i][j] = xb[i * 4 + j];
  float vv[4][4];
#pragma unroll
  for (int i = 0; i < 4; ++i)
#pragma unroll
    for (int j = 0; j < 4; ++j) vv[i][j] = (i == j) ? 1.f : 0.f;

  constexpr int P4[6] = {0, 0, 0, 1, 1, 2};
  constexpr int Q4[6] = {1, 2, 3, 2, 3, 3};
  for (int sw = 0; sw < 6; ++sw) {
#pragma unroll
    for (int e = 0; e < 6; ++e) {
      const int p = P4[e], q = Q4[e];
      float c, s;
      rot_cs(a[p][p], a[q][q], a[p][q], c, s);
#pragma unroll
      for (int j = 0; j < 4; ++j) {
        float xx = a[p][j], yy = a[q][j];
        a[p][j] = c * xx - s * yy;
        a[q][j] = s * xx + c * yy;
      }
#pragma unroll
      for (int i = 0; i < 4; ++i) {
        float xx = a[i][p], yy = a[i][q];
        a[i][p] = c * xx - s * yy;
        a[i][q] = s * xx + c * yy;
      }
#pragma unroll
      for (int i = 0; i < 4; ++i) {
        float xx = vv[i][p], yy = vv[i][q];
        vv[i][p] = c * xx - s * yy;
        vv[i][q] = s * xx + c * yy;
      }
    }
  }
  float ll[4];
#pragma unroll
  for (int r = 0; r < 4; ++r) ll[r] = logf(fmaxf(a[r][r], 1e-12f));
  float feat[16];
#pragma unroll
  for (int i = 0; i < 4; ++i)
#pragma unroll
    for (int j = 0; j < 4; ++j) {
      float acc = 0.f;
#pragma unroll
      for (int r = 0; r < 4; ++r) acc += ll[r] * vv[i][r] * vv[j][r];
      feat[i * 4 + j] = acc;
    }
  float z0 = 0.f, z1 = 0.f;
#pragma unroll
  for (int k = 0; k < 16; ++k) {
    z0 += feat[k] * fcw[2 * k + 0];
    z1 += feat[k] * fcw[2 * k + 1];
  }
  float m = fmaxf(z0, z1);
  float lse = logf(expf(z0 - m) + expf(z1 - m));
  out[b * 2 + 0] = z0 - m - lse;
  out[b * 2 + 1] = z1 - m - lse;
#pragma unroll
  for (int k = 0; k < 16; ++k) out[2 * NB + b * 16 + k] = feat[k];
}

extern "C" void kernel_launch(void* const* d_in, const int* in_sizes, int n_in,
                              void* d_out, int out_size, void* d_ws,
                              size_t ws_size, hipStream_t stream) {
  (void)in_sizes;
  (void)n_in;
  (void)out_size;
  (void)d_ws;
  (void)ws_size;
  const float* x = (const float*)d_in[0];
  const float* w1 = (const float*)d_in[1];
  const float* w2 = (const float*)d_in[2];
  const float* w3 = (const float*)d_in[3];
  const float* fcw = (const float*)d_in[4];
  float* out = (float*)d_out;

  spd_stage1<<<(NB + 5) / 6, 128, 0, stream>>>(x, w1, w2);
  spd_stage2<<<NB / 8, 128, 0, stream>>>(w3);
  spd_stage3<<<NB / 256, 256, 0, stream>>>(fcw, out);
}